// Round 6
// baseline (533.187 us; speedup 1.0000x reference)
//
#include <hip/hip_runtime.h>
#include <math.h>

#define NB 64
#define NS 2048
#define ND 512
#define MTOT (NB * NS)  // 131072
#define CCLIP 10.0f

typedef _Float16 f16x8 __attribute__((ext_vector_type(8)));
typedef _Float16 f16x4 __attribute__((ext_vector_type(4)));
typedef float f32x4 __attribute__((ext_vector_type(4)));

__device__ __forceinline__ void gl2lds16(const void* g, void* l) {
  __builtin_amdgcn_global_load_lds(
      (const __attribute__((address_space(1))) void*)(uintptr_t)g,
      (__attribute__((address_space(3))) void*)(uintptr_t)l, 16, 0, 0);
}

__device__ __forceinline__ float tanh_fast(float x) {
  float e = __expf(2.f * x);
  return 1.f - 2.f * __builtin_amdgcn_rcpf(e + 1.f);
}

__device__ __forceinline__ f16x8 cvt8(float4 a, float4 b) {
  f16x8 h;
  h[0] = (_Float16)a.x; h[1] = (_Float16)a.y;
  h[2] = (_Float16)a.z; h[3] = (_Float16)a.w;
  h[4] = (_Float16)b.x; h[5] = (_Float16)b.y;
  h[6] = (_Float16)b.z; h[7] = (_Float16)b.w;
  return h;
}

// ---------------------------------------------------------------------------
// cvtw: Wref fp32 -> fp16 permuted into exact LDS-staging order:
//   WhA[((kt*4 + kg)*512 + d)*8 + h] = Wref[d][kt*32 + kg*8 + h]
// ---------------------------------------------------------------------------
__global__ __launch_bounds__(256) void cvtw_kernel(
    const float4* __restrict__ w4, _Float16* __restrict__ WhA) {
  const int idx = blockIdx.x * 256 + threadIdx.x;  // < 65536 float4s
  const int d = idx >> 7;
  const int k = (idx & 127) << 2;
  float4 x = w4[idx];
  f16x4 o;
  o[0] = (_Float16)x.x; o[1] = (_Float16)x.y;
  o[2] = (_Float16)x.z; o[3] = (_Float16)x.w;
  const int kt = k >> 5;
  const int kg = (k >> 3) & 3;
  const int h = k & 7;
  *(f16x4*)(WhA + ((size_t)((kt * 4 + kg) * 512 + d) * 8 + h)) = o;
}

// ---------------------------------------------------------------------------
// qk: q[b,d] = sum_k W_q[d,k] * tgt[b,k]
// ---------------------------------------------------------------------------
__global__ __launch_bounds__(256) void qk_kernel(const float* __restrict__ tgt,
                                                 const float* __restrict__ Wq,
                                                 float* __restrict__ q_ws) {
  const int b = blockIdx.x >> 1;
  const int d = ((blockIdx.x & 1) << 8) + threadIdx.x;
  __shared__ float tl[ND];
  tl[threadIdx.x] = tgt[b * ND + threadIdx.x];
  tl[threadIdx.x + 256] = tgt[b * ND + threadIdx.x + 256];
  __syncthreads();
  const float4* wr = (const float4*)(Wq + (size_t)d * ND);
  float acc = 0.f;
#pragma unroll 8
  for (int k4 = 0; k4 < ND / 4; ++k4) {
    float4 w4 = wr[k4];
    acc += w4.x * tl[4 * k4 + 0] + w4.y * tl[4 * k4 + 1] +
           w4.z * tl[4 * k4 + 2] + w4.w * tl[4 * k4 + 3];
  }
  q_ws[b * ND + d] = acc;
}

// ---------------------------------------------------------------------------
// gemm: block = 64 rows x full N=512; 16 kt of K=32. 4 waves, wave tile
// 64x128, acc[4][8], 32 MFMA/wave/kt. 2-deep pipeline: A regs loaded kt+2,
// sA/sB double-buffered, ONE barrier per kt. LDS 2*4 + 2*32 + 1 = 73 KB.
// ---------------------------------------------------------------------------
__global__ __launch_bounds__(256) void gemm_kernel(
    const float* __restrict__ src, const _Float16* __restrict__ WhA,
    const float* __restrict__ q_ws, const float* __restrict__ v,
    float* __restrict__ out_logit, float* __restrict__ out_probs_w) {
  __shared__ __align__(16) _Float16 sA[2][4 * 64 * 8];   // 2 x 4 KB
  __shared__ __align__(16) _Float16 sB[2][4 * 512 * 8];  // 2 x 32 KB
  __shared__ float ured[4 * 64];                         // 1 KB

  const int tid = threadIdx.x;
  const int lane = tid & 63;
  const int w = tid >> 6;
  const int s0 = blockIdx.x << 6;
  const int bb = blockIdx.x >> 5;
  const int quad = lane >> 4;
  const int l15 = lane & 15;

  const int ar = tid & 63;
  const int akg = tid >> 6;
  const float4* ap = (const float4*)(src + ((size_t)(s0 + ar) << 9)) + akg * 2;
  const int awoff = (akg * 64 + ar) * 8;
  const char* gB = (const char*)WhA;
  const int bco = w * 8192 + lane * 16;  // this wave's B chunk base (bytes)

  // prologue: xa[0] <- A(kt0), xa[1] <- A(kt1); sB[0] <- B(kt0); sA[0] <- xa0
  float4 xa[2][2];
  xa[0][0] = ap[0]; xa[0][1] = ap[1];
  xa[1][0] = ap[8]; xa[1][1] = ap[9];
#pragma unroll
  for (int i = 0; i < 8; ++i)
    gl2lds16(gB + bco + i * 1024, (char*)sB[0] + bco + i * 1024);
  *(f16x8*)(sA[0] + awoff) = cvt8(xa[0][0], xa[0][1]);
  __syncthreads();

  f32x4 acc[4][8];
#pragma unroll
  for (int i = 0; i < 4; ++i)
#pragma unroll
    for (int j = 0; j < 8; ++j) acc[i][j] = (f32x4){0.f, 0.f, 0.f, 0.f};

#pragma unroll
  for (int kt = 0; kt < 16; ++kt) {
    const int cur = kt & 1;
    const int nxt = cur ^ 1;
    // issue A global loads for kt+2 into the just-freed reg slot
    if (kt + 2 < 16) {
      xa[cur][0] = ap[(kt + 2) * 8];
      xa[cur][1] = ap[(kt + 2) * 8 + 1];
    }
    if (kt + 1 < 16) {
      // B stage for kt+1 (L2-resident weights)
#pragma unroll
      for (int i = 0; i < 8; ++i)
        gl2lds16(gB + (size_t)(kt + 1) * 32768 + bco + i * 1024,
                 (char*)sB[nxt] + bco + i * 1024);
      // A fp16 write for kt+1 from regs loaded a full iteration ago
      *(f16x8*)(sA[nxt] + awoff) = cvt8(xa[nxt][0], xa[nxt][1]);
    }
    // compute on current buffers
    f16x8 af[4], bf[8];
#pragma unroll
    for (int i = 0; i < 4; ++i)
      af[i] = *(const f16x8*)(sA[cur] + (quad * 64 + 16 * i + l15) * 8);
#pragma unroll
    for (int j = 0; j < 8; ++j)
      bf[j] =
          *(const f16x8*)(sB[cur] + (quad * 512 + w * 128 + 16 * j + l15) * 8);
#pragma unroll
    for (int i = 0; i < 4; ++i)
#pragma unroll
      for (int j = 0; j < 8; ++j)
        acc[i][j] = __builtin_amdgcn_mfma_f32_16x16x32_f16(af[i], bf[j],
                                                           acc[i][j], 0, 0, 0);
    __syncthreads();
  }

  // epilogue: pu[row] = sum over this wave's 128 cols of tanh(C+q)*v
  float pu[4][4];
#pragma unroll
  for (int i = 0; i < 4; ++i)
#pragma unroll
    for (int r = 0; r < 4; ++r) pu[i][r] = 0.f;

#pragma unroll
  for (int j = 0; j < 8; ++j) {
    const int dl = w * 128 + 16 * j + l15;
    const float qq = q_ws[bb * ND + dl];
    const float vv = v[dl];
#pragma unroll
    for (int i = 0; i < 4; ++i) {
      f32x4 a = acc[i][j];
#pragma unroll
      for (int r = 0; r < 4; ++r) pu[i][r] += tanh_fast(a[r] + qq) * vv;
    }
  }

#pragma unroll
  for (int i = 0; i < 4; ++i)
#pragma unroll
    for (int r = 0; r < 4; ++r) {
      float x = pu[i][r];
      x += __shfl_xor(x, 1, 16);
      x += __shfl_xor(x, 2, 16);
      x += __shfl_xor(x, 4, 16);
      x += __shfl_xor(x, 8, 16);
      pu[i][r] = x;
    }

  if (l15 == 0) {
#pragma unroll
    for (int i = 0; i < 4; ++i)
#pragma unroll
      for (int r = 0; r < 4; ++r)
        ured[w * 64 + 16 * i + quad * 4 + r] = pu[i][r];
  }
  __syncthreads();
  if (tid < 64) {
    const float u =
        ured[tid] + ured[64 + tid] + ured[128 + tid] + ured[192 + tid];
    const float lg = CCLIP * tanhf(u);
    out_logit[s0 + tid] = lg;
    out_probs_w[s0 + tid] = expf(lg - CCLIP);
  }
}

// ---------------------------------------------------------------------------
// dp: block = 128 rows x 512 cols, float4/thread. 1024 blocks (16/batch).
// ---------------------------------------------------------------------------
__global__ __launch_bounds__(256) void dp_kernel(const float* __restrict__ src,
                                                 const float* __restrict__ w_ws,
                                                 float* __restrict__ dp_ws) {
  __shared__ float4 part[128];
  const int blk = blockIdx.x;
  const int b = blk >> 4;
  const int ch = blk & 15;
  const int tid = threadIdx.x;
  const int row0 = b * NS + ch * 128;
  const int c4 = (tid & 127) << 2;
  const int ro = tid >> 7;  // 0/1
  const float4* base =
      (const float4*)(src + ((size_t)(row0 + ro) << 9) + c4);
  const float* wp = w_ws + row0 + ro;
  float4 a = {0.f, 0.f, 0.f, 0.f};
#pragma unroll 8
  for (int s = 0; s < 64; ++s) {
    const float wv = wp[2 * s];
    const float4 x = base[(size_t)s * 256];
    a.x += wv * x.x; a.y += wv * x.y; a.z += wv * x.z; a.w += wv * x.w;
  }
  if (ro == 1) part[tid & 127] = a;
  __syncthreads();
  if (ro == 0) {
    const float4 p = part[tid];
    a.x += p.x; a.y += p.y; a.z += p.z; a.w += p.w;
    *(float4*)(dp_ws + (size_t)blk * ND + c4) = a;
  }
}

// ---------------------------------------------------------------------------
// fin: per b: S = sum w (in out_probs); probs *= 1/S; d' = (sum 16 parts)/S
// ---------------------------------------------------------------------------
__global__ __launch_bounds__(256) void fin_kernel(
    const float* __restrict__ dp_ws, float* __restrict__ out_dp,
    float* __restrict__ out_probs) {
  const int b = blockIdx.x;
  const int tid = threadIdx.x;
  __shared__ float red[4];
  __shared__ float s_inv;

  float x = 0.f;
  for (int idx = tid; idx < NS; idx += 256) x += out_probs[b * NS + idx];
#pragma unroll
  for (int m = 32; m; m >>= 1) x += __shfl_xor(x, m, 64);
  if ((tid & 63) == 0) red[tid >> 6] = x;
  __syncthreads();
  if (tid == 0) s_inv = 1.f / (red[0] + red[1] + red[2] + red[3]);
  __syncthreads();
  const float inv = s_inv;

  for (int idx = tid; idx < NS; idx += 256)
    out_probs[b * NS + idx] *= inv;

  for (int d = tid; d < ND; d += 256) {
    float acc = 0.f;
#pragma unroll
    for (int ch = 0; ch < 16; ++ch)
      acc += dp_ws[(size_t)(b * 16 + ch) * ND + d];
    out_dp[b * ND + d] = acc * inv;
  }
}

// ---------------------------------------------------------------------------
extern "C" void kernel_launch(void* const* d_in, const int* in_sizes, int n_in,
                              void* d_out, int out_size, void* d_ws,
                              size_t ws_size, hipStream_t stream) {
  const float* src = (const float*)d_in[0];   // [64,2048,512]
  const float* tgt = (const float*)d_in[1];   // [64,1,512]
  const float* Wq = (const float*)d_in[2];    // [512,512]
  const float* Wref = (const float*)d_in[3];  // [512,512]
  const float* v = (const float*)d_in[4];     // [512]

  float* out = (float*)d_out;
  float* out_dp = out;                        // 64*512
  float* out_probs = out + NB * ND;           // 64*2048 (holds w pre-fin)
  float* out_logit = out + NB * ND + NB * NS; // 64*2048

  // workspace: 2,752,512 B total (well under proven 4.85 MB footprint)
  char* ws = (char*)d_ws;
  _Float16* WhA = (_Float16*)ws;              // 512*512*2 =   524,288 B
  float* q_ws = (float*)(ws + 524288);        // 64*512*4  =   131,072 B
  float* dp_ws = (float*)(ws + 655360);       // 1024*512*4 = 2,097,152 B

  cvtw_kernel<<<256, 256, 0, stream>>>((const float4*)Wref, WhA);
  qk_kernel<<<2 * NB, 256, 0, stream>>>(tgt, Wq, q_ws);
  gemm_kernel<<<MTOT / 64, 256, 0, stream>>>(src, WhA, q_ws, v, out_logit,
                                             out_probs);
  dp_kernel<<<NB * 16, 256, 0, stream>>>(src, out_probs, dp_ws);
  fin_kernel<<<NB, 256, 0, stream>>>(dp_ws, out_dp, out_probs);
}